// Round 17
// baseline (370.078 us; speedup 1.0000x reference)
//
#include <hip/hip_runtime.h>
#include <hip/hip_bf16.h>

#define BB 2
#define SS 2048
#define NH 32
#define NKV 8
#define GQ (NH / NKV)
#define DD 128
#define QBLK 256
#define KVBLK 64
#define NQT (SS / QBLK)
#define NTHREADS 512
#define NWAVES 8

// +8 shorts (16B) padding on LDS leading dims (R10: conflicts 9.4e7 -> 1.8e7).
#define KPAD (DD + 8)
#define VPAD (KVBLK + 8)

typedef __bf16 bf16x8 __attribute__((ext_vector_type(8)));
typedef short short8 __attribute__((ext_vector_type(8)));
typedef float f32x4 __attribute__((ext_vector_type(4)));
typedef unsigned int u32x4 __attribute__((ext_vector_type(4)));
typedef unsigned short u16x4 __attribute__((ext_vector_type(4)));

__device__ inline bf16x8 cvt_bf16x8(float4 a, float4 b) {
  bf16x8 r;
  r[0] = (__bf16)a.x; r[1] = (__bf16)a.y; r[2] = (__bf16)a.z; r[3] = (__bf16)a.w;
  r[4] = (__bf16)b.x; r[5] = (__bf16)b.y; r[6] = (__bf16)b.z; r[7] = (__bf16)b.w;
  return r;
}

// R16's 2-subtile reuse at R15's occupancy: 8 waves x 32 q-rows (QBLK=256,
// 512 threads). Fragment reads halved per q-row AND 16 waves/CU restored.
// KV HBM re-fetch also halves (32 blocks share each kh stream).
__global__ __launch_bounds__(NTHREADS, 4)
void attn_mfma_q256w(const float* __restrict__ qp, const float* __restrict__ kp,
                     const float* __restrict__ vp, float* __restrict__ op)
{
  __shared__ __align__(16) short kpl[KVBLK][KPAD];       // 17.4KB
  __shared__ __align__(16) short vtp[DD][VPAD];          // 18.4KB
  __shared__ __align__(16) short ppl[NWAVES][32][VPAD];  // 36.9KB

  const int tid  = threadIdx.x;
  const int wave = tid >> 6;
  const int lane = tid & 63;
  const int lhi  = lane >> 4;
  const int llo  = lane & 15;

  const int bid = blockIdx.x;
  const int bh  = bid % (BB * NH);
  const int qt  = NQT - 1 - bid / (BB * NH);   // heavy q-tiles first
  const int b   = bh / NH;
  const int h   = bh % NH;
  const int kh  = h / GQ;

  const int q0 = qt * QBLK;
  const int qw = q0 + wave * 32;               // this wave's 32 rows

  const float scale = 0.08838834764831845f;    // 1/sqrt(128)

  // ---- Q fragments for both subtiles ----
  bf16x8 qf[2][4];
  #pragma unroll
  for (int u = 0; u < 2; ++u) {
    const float* qrow = qp + (((size_t)b * SS + (qw + u * 16 + llo)) * NH + h) * DD;
    #pragma unroll
    for (int kc = 0; kc < 4; ++kc) {
      const int d0 = kc * 32 + lhi * 8;
      float4 a = *(const float4*)(qrow + d0);
      float4 c = *(const float4*)(qrow + d0 + 4);
      a.x *= scale; a.y *= scale; a.z *= scale; a.w *= scale;
      c.x *= scale; c.y *= scale; c.z *= scale; c.w *= scale;
      qf[u][kc] = cvt_bf16x8(a, c);
    }
  }

  f32x4 oacc[2][8];
  #pragma unroll
  for (int u = 0; u < 2; ++u)
    #pragma unroll
    for (int f = 0; f < 8; ++f) oacc[u][f] = (f32x4){0.f, 0.f, 0.f, 0.f};
  float m_i[2] = {-1e30f, -1e30f}, l_i[2] = {0.f, 0.f};

  const int ntiles = q0 / KVBLK + QBLK / KVBLK;

  for (int t = 0; t < ntiles; ++t) {
    const int t0 = t * KVBLK;
    __syncthreads();   // previous tile's compute done before overwriting LDS

    // ---- stage K tile (bf16): 2 x 16B store per thread ----
    #pragma unroll
    for (int it = 0; it < 2; ++it) {
      const int c   = tid + it * NTHREADS;     // 0..1023
      const int row = c >> 4, c16 = c & 15;
      const float* src = kp + (((size_t)b * SS + (t0 + row)) * NKV + kh) * DD + c16 * 8;
      float4 a = *(const float4*)src;
      float4 d = *(const float4*)(src + 4);
      *(u32x4*)&kpl[row][c16 * 8] = __builtin_bit_cast(u32x4, cvt_bf16x8(a, d));
    }
    // ---- stage V^T tile: coalesced per-t dword loads -> b128 row-seg writes ----
    #pragma unroll
    for (int it = 0; it < 2; ++it) {
      const int c  = tid + it * NTHREADS;      // 0..1023
      const int dv = c & 127, t8 = c >> 7;     // d, t-octet
      const float* src = vp + (((size_t)b * SS + (t0 + t8 * 8)) * NKV + kh) * DD + dv;
      bf16x8 e;
      #pragma unroll
      for (int i = 0; i < 8; ++i)
        e[i] = (__bf16)src[(size_t)i * (NKV * DD)];
      *(u32x4*)&vtp[dv][t8 * 8] = __builtin_bit_cast(u32x4, e);
    }
    __syncthreads();

    if (t0 > qw + 31) continue;   // wave-uniform skip (barrier count unchanged)

    // ---- QK^T swapped, both subtiles share each K read ----
    f32x4 sf[2][4];
    #pragma unroll
    for (int cc = 0; cc < 4; ++cc) {
      f32x4 a0 = (f32x4){0.f, 0.f, 0.f, 0.f};
      f32x4 a1 = (f32x4){0.f, 0.f, 0.f, 0.f};
      const int r = cc * 16 + llo;             // K row for A-fragment
      #pragma unroll
      for (int kc = 0; kc < 4; ++kc) {
        u32x4 kb = *(const u32x4*)&kpl[r][(kc * 4 + lhi) * 8];
        const bf16x8 kf = __builtin_bit_cast(bf16x8, kb);
        a0 = __builtin_amdgcn_mfma_f32_16x16x32_bf16(kf, qf[0][kc], a0, 0, 0, 0);
        a1 = __builtin_amdgcn_mfma_f32_16x16x32_bf16(kf, qf[1][kc], a1, 0, 0, 0);
      }
      sf[0][cc] = a0; sf[1][cc] = a1;
    }

    // ---- causal mask (S^T layout), per subtile ----
    if (t0 + KVBLK - 1 > qw) {
      #pragma unroll
      for (int u = 0; u < 2; ++u) {
        const int qg = qw + u * 16 + llo;
        #pragma unroll
        for (int cc = 0; cc < 4; ++cc)
          #pragma unroll
          for (int j = 0; j < 4; ++j) {
            const int tg = t0 + cc * 16 + lhi * 4 + j;
            if (tg > qg) sf[u][cc][j] = -1e30f;
          }
      }
    }

    // ---- online softmax + P-store, per subtile ----
    #pragma unroll
    for (int u = 0; u < 2; ++u) {
      float tmx = sf[u][0][0];
      #pragma unroll
      for (int cc = 0; cc < 4; ++cc)
        #pragma unroll
        for (int j = 0; j < 4; ++j)
          tmx = fmaxf(tmx, sf[u][cc][j]);
      tmx = fmaxf(tmx, __shfl_xor(tmx, 16));
      tmx = fmaxf(tmx, __shfl_xor(tmx, 32));
      const float mnew = fmaxf(m_i[u], tmx);
      const float corr = __expf(m_i[u] - mnew);
      m_i[u] = mnew;
      float s = 0.f;
      #pragma unroll
      for (int cc = 0; cc < 4; ++cc)
        #pragma unroll
        for (int j = 0; j < 4; ++j) {
          const float p = __expf(sf[u][cc][j] - mnew);
          sf[u][cc][j] = p;
          s += p;
        }
      s += __shfl_xor(s, 16);
      s += __shfl_xor(s, 32);
      l_i[u] = l_i[u] * corr + s;

      #pragma unroll
      for (int j = 0; j < 4; ++j) {
        const float cj = __shfl(corr, lhi * 4 + j);
        #pragma unroll
        for (int f = 0; f < 8; ++f) oacc[u][f][j] *= cj;
      }

      #pragma unroll
      for (int cc = 0; cc < 4; ++cc) {
        u16x4 pk;
        pk[0] = __builtin_bit_cast(unsigned short, (__bf16)sf[u][cc][0]);
        pk[1] = __builtin_bit_cast(unsigned short, (__bf16)sf[u][cc][1]);
        pk[2] = __builtin_bit_cast(unsigned short, (__bf16)sf[u][cc][2]);
        pk[3] = __builtin_bit_cast(unsigned short, (__bf16)sf[u][cc][3]);
        *(u16x4*)&ppl[wave][u * 16 + llo][cc * 16 + lhi * 4] = pk;
      }
    }

    asm volatile("s_waitcnt lgkmcnt(0)" ::: "memory");
    __builtin_amdgcn_sched_barrier(0);

    // ---- PV, both subtiles share each V read ----
    #pragma unroll
    for (int kc2 = 0; kc2 < 2; ++kc2) {
      u32x4 pa0 = *(const u32x4*)&ppl[wave][llo][(kc2 * 4 + lhi) * 8];
      u32x4 pa1 = *(const u32x4*)&ppl[wave][16 + llo][(kc2 * 4 + lhi) * 8];
      #pragma unroll
      for (int f = 0; f < 8; ++f) {
        u32x4 vb = *(const u32x4*)&vtp[f * 16 + llo][(kc2 * 4 + lhi) * 8];
        const bf16x8 vf = __builtin_bit_cast(bf16x8, vb);
        oacc[0][f] = __builtin_amdgcn_mfma_f32_16x16x32_bf16(
                         __builtin_bit_cast(bf16x8, pa0), vf, oacc[0][f], 0, 0, 0);
        oacc[1][f] = __builtin_amdgcn_mfma_f32_16x16x32_bf16(
                         __builtin_bit_cast(bf16x8, pa1), vf, oacc[1][f], 0, 0, 0);
      }
    }
  }

  // ---- epilogue: O / l ----
  #pragma unroll
  for (int u = 0; u < 2; ++u)
    #pragma unroll
    for (int j = 0; j < 4; ++j) {
      const float lj = __shfl(l_i[u], lhi * 4 + j);
      const float inv = 1.f / lj;
      const int qg = qw + u * 16 + lhi * 4 + j;
      float* orow = op + (((size_t)b * SS + qg) * NH + h) * DD;
      #pragma unroll
      for (int f = 0; f < 8; ++f)
        orow[f * 16 + llo] = oacc[u][f][j] * inv;
    }
}

extern "C" void kernel_launch(void* const* d_in, const int* in_sizes, int n_in,
                              void* d_out, int out_size, void* d_ws, size_t ws_size,
                              hipStream_t stream) {
  const float* q = (const float*)d_in[0];
  const float* k = (const float*)d_in[1];
  const float* v = (const float*)d_in[2];
  float* out = (float*)d_out;
  dim3 grid(BB * NH * NQT);   // 512 blocks
  dim3 block(NTHREADS);
  attn_mfma_q256w<<<grid, block, 0, stream>>>(q, k, v, out);
}

// Round 18
// 147.976 us; speedup vs baseline: 2.5009x; 2.5009x over previous
//
#include <hip/hip_runtime.h>
#include <hip/hip_bf16.h>

#define BB 2
#define SS 2048
#define NH 32
#define NKV 8
#define GQ (NH / NKV)
#define DD 128
#define QBLK 256
#define KVBLK 64
#define NQT (SS / QBLK)
#define NTHREADS 512
#define NWAVES 8

// +8 shorts (16B) padding on LDS leading dims (R10: conflicts 9.4e7 -> 1.8e7).
#define KPAD (DD + 8)
#define VPAD (KVBLK + 8)

typedef __bf16 bf16x8 __attribute__((ext_vector_type(8)));
typedef short short8 __attribute__((ext_vector_type(8)));
typedef float f32x4 __attribute__((ext_vector_type(4)));
typedef unsigned int u32x4 __attribute__((ext_vector_type(4)));
typedef unsigned short u16x4 __attribute__((ext_vector_type(4)));

__device__ inline bf16x8 cvt_bf16x8(float4 a, float4 b) {
  bf16x8 r;
  r[0] = (__bf16)a.x; r[1] = (__bf16)a.y; r[2] = (__bf16)a.z; r[3] = (__bf16)a.w;
  r[4] = (__bf16)b.x; r[5] = (__bf16)b.y; r[6] = (__bf16)b.z; r[7] = (__bf16)b.w;
  return r;
}

// R17 with the register cap fixed: __launch_bounds__(512, 2) -> VGPR cap 256
// (R17's (512,4) capped at 128 -> 64-reg alloc + scratch spill, 1.1GB HBM).
// Occupancy is LDS-bound: 72.7KB -> 2 blocks/CU -> 16 waves/CU.
__global__ __launch_bounds__(NTHREADS, 2)
void attn_mfma_q256w(const float* __restrict__ qp, const float* __restrict__ kp,
                     const float* __restrict__ vp, float* __restrict__ op)
{
  __shared__ __align__(16) short kpl[KVBLK][KPAD];       // 17.4KB
  __shared__ __align__(16) short vtp[DD][VPAD];          // 18.4KB
  __shared__ __align__(16) short ppl[NWAVES][32][VPAD];  // 36.9KB

  const int tid  = threadIdx.x;
  const int wave = tid >> 6;
  const int lane = tid & 63;
  const int lhi  = lane >> 4;
  const int llo  = lane & 15;

  const int bid = blockIdx.x;
  const int bh  = bid % (BB * NH);
  const int qt  = NQT - 1 - bid / (BB * NH);   // heavy q-tiles first
  const int b   = bh / NH;
  const int h   = bh % NH;
  const int kh  = h / GQ;

  const int q0 = qt * QBLK;
  const int qw = q0 + wave * 32;               // this wave's 32 rows

  const float scale = 0.08838834764831845f;    // 1/sqrt(128)

  // ---- Q fragments for both subtiles ----
  bf16x8 qf[2][4];
  #pragma unroll
  for (int u = 0; u < 2; ++u) {
    const float* qrow = qp + (((size_t)b * SS + (qw + u * 16 + llo)) * NH + h) * DD;
    #pragma unroll
    for (int kc = 0; kc < 4; ++kc) {
      const int d0 = kc * 32 + lhi * 8;
      float4 a = *(const float4*)(qrow + d0);
      float4 c = *(const float4*)(qrow + d0 + 4);
      a.x *= scale; a.y *= scale; a.z *= scale; a.w *= scale;
      c.x *= scale; c.y *= scale; c.z *= scale; c.w *= scale;
      qf[u][kc] = cvt_bf16x8(a, c);
    }
  }

  f32x4 oacc[2][8];
  #pragma unroll
  for (int u = 0; u < 2; ++u)
    #pragma unroll
    for (int f = 0; f < 8; ++f) oacc[u][f] = (f32x4){0.f, 0.f, 0.f, 0.f};
  float m_i[2] = {-1e30f, -1e30f}, l_i[2] = {0.f, 0.f};

  const int ntiles = q0 / KVBLK + QBLK / KVBLK;

  for (int t = 0; t < ntiles; ++t) {
    const int t0 = t * KVBLK;
    __syncthreads();   // previous tile's compute done before overwriting LDS

    // ---- stage K tile (bf16): 2 x 16B store per thread ----
    #pragma unroll
    for (int it = 0; it < 2; ++it) {
      const int c   = tid + it * NTHREADS;     // 0..1023
      const int row = c >> 4, c16 = c & 15;
      const float* src = kp + (((size_t)b * SS + (t0 + row)) * NKV + kh) * DD + c16 * 8;
      float4 a = *(const float4*)src;
      float4 d = *(const float4*)(src + 4);
      *(u32x4*)&kpl[row][c16 * 8] = __builtin_bit_cast(u32x4, cvt_bf16x8(a, d));
    }
    // ---- stage V^T tile: coalesced per-t dword loads -> b128 row-seg writes ----
    #pragma unroll
    for (int it = 0; it < 2; ++it) {
      const int c  = tid + it * NTHREADS;      // 0..1023
      const int dv = c & 127, t8 = c >> 7;     // d, t-octet
      const float* src = vp + (((size_t)b * SS + (t0 + t8 * 8)) * NKV + kh) * DD + dv;
      bf16x8 e;
      #pragma unroll
      for (int i = 0; i < 8; ++i)
        e[i] = (__bf16)src[(size_t)i * (NKV * DD)];
      *(u32x4*)&vtp[dv][t8 * 8] = __builtin_bit_cast(u32x4, e);
    }
    __syncthreads();

    if (t0 > qw + 31) continue;   // wave-uniform skip (barrier count unchanged)

    // ---- QK^T swapped, both subtiles share each K read ----
    f32x4 sf[2][4];
    #pragma unroll
    for (int cc = 0; cc < 4; ++cc) {
      f32x4 a0 = (f32x4){0.f, 0.f, 0.f, 0.f};
      f32x4 a1 = (f32x4){0.f, 0.f, 0.f, 0.f};
      const int r = cc * 16 + llo;             // K row for A-fragment
      #pragma unroll
      for (int kc = 0; kc < 4; ++kc) {
        u32x4 kb = *(const u32x4*)&kpl[r][(kc * 4 + lhi) * 8];
        const bf16x8 kf = __builtin_bit_cast(bf16x8, kb);
        a0 = __builtin_amdgcn_mfma_f32_16x16x32_bf16(kf, qf[0][kc], a0, 0, 0, 0);
        a1 = __builtin_amdgcn_mfma_f32_16x16x32_bf16(kf, qf[1][kc], a1, 0, 0, 0);
      }
      sf[0][cc] = a0; sf[1][cc] = a1;
    }

    // ---- causal mask (S^T layout), per subtile ----
    if (t0 + KVBLK - 1 > qw) {
      #pragma unroll
      for (int u = 0; u < 2; ++u) {
        const int qg = qw + u * 16 + llo;
        #pragma unroll
        for (int cc = 0; cc < 4; ++cc)
          #pragma unroll
          for (int j = 0; j < 4; ++j) {
            const int tg = t0 + cc * 16 + lhi * 4 + j;
            if (tg > qg) sf[u][cc][j] = -1e30f;
          }
      }
    }

    // ---- online softmax + P-store, per subtile ----
    #pragma unroll
    for (int u = 0; u < 2; ++u) {
      float tmx = sf[u][0][0];
      #pragma unroll
      for (int cc = 0; cc < 4; ++cc)
        #pragma unroll
        for (int j = 0; j < 4; ++j)
          tmx = fmaxf(tmx, sf[u][cc][j]);
      tmx = fmaxf(tmx, __shfl_xor(tmx, 16));
      tmx = fmaxf(tmx, __shfl_xor(tmx, 32));
      const float mnew = fmaxf(m_i[u], tmx);
      const float corr = __expf(m_i[u] - mnew);
      m_i[u] = mnew;
      float s = 0.f;
      #pragma unroll
      for (int cc = 0; cc < 4; ++cc)
        #pragma unroll
        for (int j = 0; j < 4; ++j) {
          const float p = __expf(sf[u][cc][j] - mnew);
          sf[u][cc][j] = p;
          s += p;
        }
      s += __shfl_xor(s, 16);
      s += __shfl_xor(s, 32);
      l_i[u] = l_i[u] * corr + s;

      #pragma unroll
      for (int j = 0; j < 4; ++j) {
        const float cj = __shfl(corr, lhi * 4 + j);
        #pragma unroll
        for (int f = 0; f < 8; ++f) oacc[u][f][j] *= cj;
      }

      #pragma unroll
      for (int cc = 0; cc < 4; ++cc) {
        u16x4 pk;
        pk[0] = __builtin_bit_cast(unsigned short, (__bf16)sf[u][cc][0]);
        pk[1] = __builtin_bit_cast(unsigned short, (__bf16)sf[u][cc][1]);
        pk[2] = __builtin_bit_cast(unsigned short, (__bf16)sf[u][cc][2]);
        pk[3] = __builtin_bit_cast(unsigned short, (__bf16)sf[u][cc][3]);
        *(u16x4*)&ppl[wave][u * 16 + llo][cc * 16 + lhi * 4] = pk;
      }
    }

    asm volatile("s_waitcnt lgkmcnt(0)" ::: "memory");
    __builtin_amdgcn_sched_barrier(0);

    // ---- PV, both subtiles share each V read ----
    #pragma unroll
    for (int kc2 = 0; kc2 < 2; ++kc2) {
      u32x4 pa0 = *(const u32x4*)&ppl[wave][llo][(kc2 * 4 + lhi) * 8];
      u32x4 pa1 = *(const u32x4*)&ppl[wave][16 + llo][(kc2 * 4 + lhi) * 8];
      #pragma unroll
      for (int f = 0; f < 8; ++f) {
        u32x4 vb = *(const u32x4*)&vtp[f * 16 + llo][(kc2 * 4 + lhi) * 8];
        const bf16x8 vf = __builtin_bit_cast(bf16x8, vb);
        oacc[0][f] = __builtin_amdgcn_mfma_f32_16x16x32_bf16(
                         __builtin_bit_cast(bf16x8, pa0), vf, oacc[0][f], 0, 0, 0);
        oacc[1][f] = __builtin_amdgcn_mfma_f32_16x16x32_bf16(
                         __builtin_bit_cast(bf16x8, pa1), vf, oacc[1][f], 0, 0, 0);
      }
    }
  }

  // ---- epilogue: O / l ----
  #pragma unroll
  for (int u = 0; u < 2; ++u)
    #pragma unroll
    for (int j = 0; j < 4; ++j) {
      const float lj = __shfl(l_i[u], lhi * 4 + j);
      const float inv = 1.f / lj;
      const int qg = qw + u * 16 + lhi * 4 + j;
      float* orow = op + (((size_t)b * SS + qg) * NH + h) * DD;
      #pragma unroll
      for (int f = 0; f < 8; ++f)
        orow[f * 16 + llo] = oacc[u][f][j] * inv;
    }
}

extern "C" void kernel_launch(void* const* d_in, const int* in_sizes, int n_in,
                              void* d_out, int out_size, void* d_ws, size_t ws_size,
                              hipStream_t stream) {
  const float* q = (const float*)d_in[0];
  const float* k = (const float*)d_in[1];
  const float* v = (const float*)d_in[2];
  float* out = (float*)d_out;
  dim3 grid(BB * NH * NQT);   // 512 blocks
  dim3 block(NTHREADS);
  attn_mfma_q256w<<<grid, block, 0, stream>>>(q, k, v, out);
}